// Round 5
// baseline (202.498 us; speedup 1.0000x reference)
//
#include <hip/hip_runtime.h>
#include <hip/hip_bf16.h>

typedef __attribute__((ext_vector_type(8))) short short8;
typedef __attribute__((ext_vector_type(4))) short s16x4;
typedef __attribute__((ext_vector_type(4))) float f32x4;
typedef unsigned short u16;

// round-to-nearest-even fp32 -> bf16
__device__ inline u16 f2bf(float f) {
    union { float f; unsigned u; } x{f};
    unsigned r = (x.u + 0x7fff + ((x.u >> 16) & 1)) >> 16;
    return (u16)r;
}

// pack two fp32 -> packed bf16 pair (round-half-up via +0x8000, then v_perm)
__device__ inline unsigned pkbf(float hi, float lo) {
    unsigned a = __builtin_bit_cast(unsigned, hi) + 0x8000u;
    unsigned b = __builtin_bit_cast(unsigned, lo) + 0x8000u;
    return __builtin_amdgcn_perm(a, b, 0x07060302u);
}

// async 16B global -> LDS (wave-uniform base + lane*16 layout)
__device__ inline void glds16(const u16* g, u16* l) {
    __builtin_amdgcn_global_load_lds(
        (const __attribute__((address_space(1))) void*)g,
        (__attribute__((address_space(3))) void*)l, 16, 0, 0);
}

// ---------------- fused prep: cvt x -> bf16 | transpose w_in | w_out --------
__global__ __launch_bounds__(256) void prep(const float* __restrict__ x,
                                            const float* __restrict__ w_in,
                                            const float* __restrict__ w_out,
                                            u16* __restrict__ Xb,
                                            u16* __restrict__ WtIn,
                                            u16* __restrict__ WtOut) {
    __shared__ float tile[32][33];
    int bx = blockIdx.x, tid = threadIdx.x;
    if (bx < 4096) {
        int i = (bx * 256 + tid) * 4;
        float4 v = *(const float4*)&x[i];
        uint2 o;
        o.x = (unsigned)f2bf(v.x) | ((unsigned)f2bf(v.y) << 16);
        o.y = (unsigned)f2bf(v.z) | ((unsigned)f2bf(v.w) << 16);
        *(uint2*)&Xb[i] = o;
        return;
    }
    const float* W; u16* Wt; int K, N, n0, k0;
    if (bx < 7168) {
        int b2 = bx - 4096;                 // w_in: K=1024, N=3072
        W = w_in; Wt = WtIn; K = 1024; N = 3072;
        n0 = (b2 % 96) * 32; k0 = (b2 / 96) * 32;
    } else {
        int b3 = bx - 7168;                 // w_out: K=1024, N=1024
        W = w_out; Wt = WtOut; K = 1024; N = 1024;
        n0 = (b3 & 31) * 32; k0 = (b3 >> 5) * 32;
    }
    int tx = tid & 31, ty = tid >> 5;
    for (int i = 0; i < 32; i += 8)
        tile[ty + i][tx] = W[(size_t)(k0 + ty + i) * N + n0 + tx];
    __syncthreads();
    for (int i = 0; i < 32; i += 8)
        Wt[(size_t)(n0 + ty + i) * K + k0 + tx] = f2bf(tile[tx][ty + i]);
}

// ---------------- gemm1: 256x256 tile, 8 waves, counted-vmcnt pipeline ------
// Round 13 fix of round-12's failed phase port (76us, MfmaUtil 12%, VALU 7%:
// pure stall). Root cause: T3 without T4 — the end-of-tile __syncthreads
// drained DMA issued ONE PHASE earlier, exposing full load latency every
// K-tile, with 1 block/CU (128KB LDS) and nothing to hide it. Corrected
// schedule (m201 discipline):
//  * stage the ENTIRE K-tile kt+1 at the TOP of tile kt (8 glds16/thread),
//    right after kt-1's last barrier (slot s^1 provably consumed);
//  * s_waitcnt vmcnt(8): tile kt+1's 8 loads stay IN FLIGHT, everything
//    older (tile kt, issued one full K-tile ago) is drained. vmcnt(0) only
//    at kt=15. No full drain in the main loop — T4.
//  * 4 lockstep compute phases {ds_read subtile | barrier | setprio(1)
//    16 MFMA setprio(0) | barrier} — T3 structure, T5 pays inside it.
//  * bfr held across the tile (phase 0: 12 ds_reads, phases 1-3: 4).
//  * bijective XCD swizzle (192 blocks % 8 == 0).
// LDS layout / staging addresses / fragment swizzles / epilogue identical to
// the correctness-passing round-12 kernel.
__global__ __launch_bounds__(512, 2) void gemm1_256(const u16* __restrict__ A,
                                                    const u16* __restrict__ Bt,
                                                    const float* __restrict__ bias,
                                                    u16* __restrict__ C,
                                                    u16* __restrict__ vt,
                                                    float qscale) {
    __shared__ u16 smem[2][2][256 * 64];   // [slot][A=0/B=1], 128 KiB
    int tid = threadIdx.x;
    int wave = tid >> 6, lane = tid & 63;
    int quad = lane >> 4, l16 = lane & 15;
    int wm = (wave >> 2) * 128, wn = (wave & 3) * 64;
    int bx = blockIdx.x;                   // 192 blocks; 8 XCDs x 24
    int nb = (bx & 7) * 24 + (bx >> 3);    // bijective XCD chunking
    int bm = nb / 12, bn = nb % 12;
    int m0 = bm * 256, n0 = bn * 256;

    // stage full K-tile kt (A then B) into slot s: 8 glds16 per thread.
    auto stage_tile = [&](int kt, int s) {
        int k0 = kt * 64;
        #pragma unroll
        for (int op = 0; op < 2; op++) {
            const u16* G = op ? Bt : A;
            int base0 = op ? n0 : m0;
            u16* dst = &smem[s][op][0];
            #pragma unroll
            for (int i = 0; i < 4; i++) {
                int c = tid + i * 512;      // 2048 chunks of 16B
                int r = c >> 3, cc = c & 7;
                int gsrc = (cc ^ (r & 7)) * 8;  // XOR swizzle
                glds16(&G[(size_t)(base0 + r) * 1024 + k0 + gsrc], dst + c * 8);
            }
        }
    };

    stage_tile(0, 0);

    f32x4 acc[8][4] = {};

    for (int kt = 0; kt < 16; kt++) {
        int s = kt & 1;
        const u16* As = &smem[s][0][0];
        const u16* Bs = &smem[s][1][0];

        // top of tile: issue next tile's DMA, counted wait, validate barrier
        if (kt + 1 < 16) {
            stage_tile(kt + 1, s ^ 1);
            __asm__ volatile("s_waitcnt vmcnt(8)" ::: "memory");
        } else {
            __asm__ volatile("s_waitcnt vmcnt(0)" ::: "memory");
        }
        __builtin_amdgcn_s_barrier();       // slot s valid for all waves

        short8 bfr[4][2];
        #pragma unroll
        for (int p = 0; p < 4; p++) {
            if (p == 0) {                   // B frags: held all 4 phases
                #pragma unroll
                for (int j = 0; j < 4; j++) {
                    int row = wn + j * 16 + l16;
                    bfr[j][0] = *(short8*)&Bs[row * 64 + ((0 + quad) ^ (row & 7)) * 8];
                    bfr[j][1] = *(short8*)&Bs[row * 64 + ((4 + quad) ^ (row & 7)) * 8];
                }
            }
            short8 afr[2][2];
            #pragma unroll
            for (int ii = 0; ii < 2; ii++) {
                int row = wm + (p * 2 + ii) * 16 + l16;
                afr[ii][0] = *(short8*)&As[row * 64 + ((0 + quad) ^ (row & 7)) * 8];
                afr[ii][1] = *(short8*)&As[row * 64 + ((4 + quad) ^ (row & 7)) * 8];
            }
            __builtin_amdgcn_s_barrier();   // lockstep phase issue
            __builtin_amdgcn_s_setprio(1);
            #pragma unroll
            for (int ii = 0; ii < 2; ii++)
                #pragma unroll
                for (int j = 0; j < 4; j++)
                    #pragma unroll
                    for (int ks = 0; ks < 2; ks++)
                        acc[p * 2 + ii][j] = __builtin_amdgcn_mfma_f32_16x16x32_bf16(
                            afr[ii][ks], bfr[j][ks], acc[p * 2 + ii][j], 0, 0, 0);
            __builtin_amdgcn_s_setprio(0);
            __builtin_amdgcn_s_barrier();   // phase end
        }
    }
    __syncthreads();

    // epilogue: acc -> bf16(bias, qscale) -> LDS repack -> stores (+ V^T)
    float scl = (n0 < 1024) ? qscale : 1.f;
    u16* buf = &smem[0][0][0];              // [256][256] overlay, 128 KiB
    #pragma unroll
    for (int i = 0; i < 8; i++)
        #pragma unroll
        for (int j = 0; j < 4; j++) {
            int col = wn + j * 16 + l16;
            float bv = bias[n0 + col];
            #pragma unroll
            for (int r = 0; r < 4; r++) {
                int row = wm + i * 16 + quad * 4 + r;
                buf[row * 256 + col] = f2bf((acc[i][j][r] + bv) * scl);
            }
        }
    __syncthreads();
    for (int it = 0; it < 16; it++) {
        int c = tid + it * 512;
        int row = c >> 5, k8 = c & 31;
        uint4 v = *(uint4*)&buf[row * 256 + k8 * 8];
        *(uint4*)&C[(size_t)(m0 + row) * 3072 + n0 + k8 * 8] = v;
    }
    if (n0 >= 2048) {                       // fused V^T: vt[b,h,dh,S]
        int b = m0 >> 11, s0 = m0 & 2047;
        int hbase = (n0 - 2048) >> 6;
        for (int pass = 0; pass < 16; pass++) {
            int col = pass * 16 + (tid >> 5);
            int so = (tid & 31) * 8;
            alignas(16) u16 tmp[8];
            #pragma unroll
            for (int r = 0; r < 8; r++) tmp[r] = buf[(so + r) * 256 + col];
            int h = hbase + (col >> 6), dh = col & 63;
            *(uint4*)&vt[(size_t)((b * 16 + h) * 64 + dh) * 2048 + s0 + so] =
                __builtin_bit_cast(uint4, tmp);
        }
    }
}

// ---------------- GEMM: C[M][N] = A[M][K] @ Bt[N][K]^T + bias ---------------
// (used for gemm2 only now: 64x128 tile -> 512 blocks = 2/CU)
#define BK 64
template<int TBM, int TBN>
__global__ __launch_bounds__(256) void gemm_bt(const u16* __restrict__ A,
                                               const u16* __restrict__ Bt,
                                               const float* __restrict__ bias,
                                               void* __restrict__ C,
                                               int M, int N, int K, int c_is_f32,
                                               int qcols, float qscale,
                                               u16* __restrict__ vt, int vcol0) {
    __shared__ u16 smem[TBM * BK + TBN * BK + 2048];
    u16* As = smem;
    u16* Bs = smem + TBM * BK;

    int tid = threadIdx.x;
    int wave = tid >> 6, lane = tid & 63;
    int quad = lane >> 4, l16 = lane & 15;
    int wm = (wave >> 1) * (TBM / 2), wn = (wave & 1) * (TBN / 2);
    constexpr int MI = TBM / 32, NJ = TBN / 32;

    int nm = M / TBM, nn = N / TBN;
    const int GM = 8;
    int per_group = GM * nn;
    int group = blockIdx.x / per_group;
    int rem = blockIdx.x % per_group;
    int first_m = group * GM;
    int gsz = (nm - first_m < GM) ? (nm - first_m) : GM;
    int m0 = (first_m + rem % gsz) * TBM;
    int n0 = (rem / gsz) * TBN;

    f32x4 acc[MI][NJ] = {};

    for (int k0 = 0; k0 < K; k0 += BK) {
        __syncthreads();
        for (int i = 0; i < TBM * 8 / 256; i++) {
            int c = tid + i * 256;
            int r = c >> 3, cc = c & 7;
            int gsrc = (cc ^ (r & 7)) * 8;          // XOR swizzle
            glds16(&A[(size_t)(m0 + r) * K + k0 + gsrc], As + c * 8);
        }
        for (int i = 0; i < TBN * 8 / 256; i++) {
            int c = tid + i * 256;
            int r = c >> 3, cc = c & 7;
            int gsrc = (cc ^ (r & 7)) * 8;
            glds16(&Bt[(size_t)(n0 + r) * K + k0 + gsrc], Bs + c * 8);
        }
        __syncthreads();
        for (int ks = 0; ks < 2; ks++) {
            short8 af[MI], bf[NJ];
            for (int i = 0; i < MI; i++) {
                int row = wm + i * 16 + l16;
                int slot = (ks * 4 + quad) ^ (row & 7);
                af[i] = *(short8*)&As[row * BK + slot * 8];
            }
            for (int j = 0; j < NJ; j++) {
                int row = wn + j * 16 + l16;
                int slot = (ks * 4 + quad) ^ (row & 7);
                bf[j] = *(short8*)&Bs[row * BK + slot * 8];
            }
            for (int i = 0; i < MI; i++)
                for (int j = 0; j < NJ; j++)
                    acc[i][j] = __builtin_amdgcn_mfma_f32_16x16x32_bf16(
                        af[i], bf[j], acc[i][j], 0, 0, 0);
        }
    }

    if (c_is_f32) {
        for (int i = 0; i < MI; i++)
            for (int j = 0; j < NJ; j++) {
                int col = n0 + wn + j * 16 + l16;
                float bv = bias ? bias[col] : 0.f;
                for (int r = 0; r < 4; r++) {
                    int row = m0 + wm + i * 16 + quad * 4 + r;
                    ((float*)C)[(size_t)row * N + col] = acc[i][j][r] + bv;
                }
            }
    } else {
        __syncthreads();
        u16 (*buf)[136] = (u16(*)[136])smem;
        for (int i = 0; i < MI; i++)
            for (int j = 0; j < NJ; j++) {
                int col = wn + j * 16 + l16;
                float bv = bias ? bias[n0 + col] : 0.f;
                float scl = (n0 + col < qcols) ? qscale : 1.f;
                for (int r = 0; r < 4; r++)
                    buf[wm + i * 16 + quad * 4 + r][col] =
                        f2bf((acc[i][j][r] + bv) * scl);
            }
        __syncthreads();
        u16* Cb = (u16*)C;
        for (int it = 0; it < TBM * 16 / 256; it++) {
            int c = tid + it * 256;
            int row = c / (TBN / 8), k8 = c % (TBN / 8);
            uint4 v = *(uint4*)&buf[row][k8 * 8];
            *(uint4*)&Cb[(size_t)(m0 + row) * N + n0 + k8 * 8] = v;
        }
        if (vt && n0 >= vcol0) {
            int b = m0 >> 11, s0 = m0 & 2047;
            int hbase = (n0 - vcol0) >> 6;
            for (int pass = 0; pass < TBN / 16; pass++) {
                int col = pass * 16 + (tid >> 4);
                int so = (tid & 15) * 8;
                alignas(16) u16 tmp[8];
                for (int r = 0; r < 8; r++) tmp[r] = buf[so + r][col];
                int h = hbase + (col >> 6), dh = col & 63;
                *(uint4*)&vt[(size_t)((b * 16 + h) * 64 + dh) * 2048 + s0 + so] =
                    __builtin_bit_cast(uint4, tmp);
            }
        }
    }
}

// ---------------- flash attention (causal), 32 q-rows per wave --------------
// (unchanged: dual chains, chain-sequenced schedule, setprio, O^T epilogue,
// 2 blocks/CU)
__global__ __launch_bounds__(256, 2) void attn_kernel(const u16* __restrict__ qkv,
                                                      const u16* __restrict__ VT,
                                                      u16* __restrict__ out) {
    const int S = 2048, D = 1024, stride = 3072;
    int idx = blockIdx.x;                 // 512 blocks
    int slot = idx >> 8;                  // 0: heavy half, 1: light half
    int r5 = idx & 255;
    int p = r5 >> 5, bh = r5 & 31;
    int qt = slot ? p : 15 - p;           // q-tile (128 rows) index
    int b = bh >> 4, h = bh & 15;
    int tid = threadIdx.x;                // 256
    int wave = tid >> 6, lane = tid & 63;
    int quad = lane >> 4, l16 = lane & 15;

    __shared__ u16 Klds[2][2][64 * 64];   // [dbuf][chain]; XOR-swizzled rows
    __shared__ u16 Vlds[2][2][64 * 64];

    const u16* Qp = qkv + (size_t)(b * S) * stride + h * 64;
    const u16* Kp = Qp + D;
    const u16* Vtp = VT + (size_t)bh * 64 * S;

    // Q fragments: [q-half][k-half]; wave owns rows qt*128 + wave*32 + 0..31
    short8 qf[2][2];
    for (int qh = 0; qh < 2; qh++) {
        int qrow = qt * 128 + wave * 32 + qh * 16 + l16;
        qf[qh][0] = *(const short8*)&Qp[(size_t)qrow * stride + quad * 8];
        qf[qh][1] = *(const short8*)&Qp[(size_t)qrow * stride + 32 + quad * 8];
    }

    auto stage = [&](int kt, int bsel, int ch) {
        for (int i = 0; i < 2; i++) {
            int c = tid + i * 256;        // 512 chunks of 16B each for K and V
            int rr = c >> 3, cc = c & 7;
            int gsrc = (cc ^ (rr & 7)) * 8;
            glds16(&Kp[(size_t)(kt * 64 + rr) * stride + gsrc],
                   &Klds[bsel][ch][c * 8]);
            glds16(&Vtp[(size_t)rr * S + kt * 64 + gsrc],
                   &Vlds[bsel][ch][c * 8]);
        }
    };

    stage(0, 0, 0);
    stage(1, 0, 1);

    f32x4 O[4][2] = {};                   // [db][qh], O^T fragments
    float ls[2] = {0.f, 0.f};             // row-sum partials per q-half

    int np = qt + 1;                      // pairs of 64-k tiles (exact causal)
    for (int j = 0; j < np; j++) {
        int cur = j & 1;
        __syncthreads();                  // drains DMA for this pair
        if (j + 1 < np) {
            stage(2 * (j + 1), cur ^ 1, 0);
            stage(2 * (j + 1) + 1, cur ^ 1, 1);
        }
        bool last = (j == qt);

        // ---- QK^T for one chain -> st[qh][nb]
        auto qk = [&](int ch, f32x4 st[2][4]) {
            short8 kf[4][2];
            for (int nb = 0; nb < 4; nb++) {
                int rr = nb * 16 + l16;
                int s0 = ((0 + quad) ^ (rr & 7)) * 8;
                int s1 = ((4 + quad) ^ (rr & 7)) * 8;
                kf[nb][0] = *(short8*)&Klds[cur][ch][rr * 64 + s0];
                kf[nb][1] = *(short8*)&Klds[cur][ch][rr * 64 + s1];
            }
            for (int qh = 0; qh < 2; qh++)
                for (int nb = 0; nb < 4; nb++) {
                    f32x4 t = {};
                    t = __builtin_amdgcn_mfma_f32_16x16x32_bf16(
                        kf[nb][0], qf[qh][0], t, 0, 0, 0);
                    t = __builtin_amdgcn_mfma_f32_16x16x32_bf16(
                        kf[nb][1], qf[qh][1], t, 0, 0, 0);
                    st[qh][nb] = t;
                }
        };
        // ---- softmax numerators + pack for one chain
        auto sm = [&](int ch, f32x4 st[2][4], s16x4 pfc[2][4]) {
            for (int qh = 0; qh < 2; qh++) {
                if (last) {
                    int qabs = qt * 128 + wave * 32 + qh * 16 + l16;
                    for (int nb = 0; nb < 4; nb++) {
                        int kb0 = (2 * j + ch) * 64 + nb * 16 + quad * 4;
                        for (int r = 0; r < 4; r++) {
                            float e = __builtin_amdgcn_exp2f(st[qh][nb][r]);
                            st[qh][nb][r] = (kb0 + r <= qabs) ? e : 0.f;
                        }
                    }
                } else {
                    for (int nb = 0; nb < 4; nb++)
                        for (int r = 0; r < 4; r++)
                            st[qh][nb][r] = __builtin_amdgcn_exp2f(st[qh][nb][r]);
                }
                for (int nb = 0; nb < 4; nb++) {
                    ls[qh] += (st[qh][nb][0] + st[qh][nb][1]) +
                              (st[qh][nb][2] + st[qh][nb][3]);
                    uint2 pk;
                    pk.x = pkbf(st[qh][nb][1], st[qh][nb][0]);
                    pk.y = pkbf(st[qh][nb][3], st[qh][nb][2]);
                    pfc[qh][nb] = __builtin_bit_cast(s16x4, pk);
                }
            }
        };
        // ---- PV for one chain (O^T accumulate)
        auto pv = [&](int ch, s16x4 pfc[2][4]) {
            for (int db = 0; db < 4; db++) {
                int rr = db * 16 + l16;
                for (int kc = 0; kc < 4; kc++) {
                    int g = kc * 2 + (quad >> 1);
                    int sl = g ^ (rr & 7);
                    int off = rr * 64 + sl * 8 + (quad & 1) * 4;
                    s16x4 vf = *(s16x4*)&Vlds[cur][ch][off];
                    for (int qh = 0; qh < 2; qh++)
                        O[db][qh] = __builtin_amdgcn_mfma_f32_16x16x16bf16_1k(
                            vf, pfc[qh][kc], O[db][qh], 0, 0, 0);
                }
            }
        };

        f32x4 stA[2][4], stB[2][4];
        s16x4 pfA[2][4], pfB[2][4];

        __builtin_amdgcn_s_setprio(1);
        qk(0, stA);
        __builtin_amdgcn_s_setprio(0);
        sm(0, stA, pfA);
        __builtin_amdgcn_s_setprio(1);
        qk(1, stB);                       // MFMA cluster: chain-B QK ...
        pv(0, pfA);                       // ... + chain-A PV (independent of
        __builtin_amdgcn_s_setprio(0);    //     chain-B softmax -> overlaps it)
        sm(1, stB, pfB);
        __builtin_amdgcn_s_setprio(1);
        pv(1, pfB);
        __builtin_amdgcn_s_setprio(0);
    }

    // epilogue: O^T -> each lane holds dh=db*16+quad*4+r for its own q=l16.
    for (int qh = 0; qh < 2; qh++) {
        float v = ls[qh];
        v += __shfl_xor(v, 16);
        v += __shfl_xor(v, 32);           // full row sum for q=l16
        float rinv = 1.f / v;
        int qrow = qt * 128 + wave * 32 + qh * 16 + l16;
        for (int db = 0; db < 4; db++) {
            uint2 o;
            o.x = pkbf(O[db][qh][1] * rinv, O[db][qh][0] * rinv);
            o.y = pkbf(O[db][qh][3] * rinv, O[db][qh][2] * rinv);
            *(uint2*)&out[(size_t)(b * S + qrow) * D + h * 64 + db * 16 +
                          quad * 4] = o;
        }
    }
}

// ---------------------------------------------------------------------------
extern "C" void kernel_launch(void* const* d_in, const int* in_sizes, int n_in,
                              void* d_out, int out_size, void* d_ws, size_t ws_size,
                              hipStream_t stream) {
    const float* x     = (const float*)d_in[0];
    const float* w_in  = (const float*)d_in[1];
    const float* b_in  = (const float*)d_in[2];
    const float* w_out = (const float*)d_in[3];
    const float* b_out = (const float*)d_in[4];

    const int Bsz = 2, S = 2048, D = 1024, H = 16;
    const int M = Bsz * S;
    const int N1 = 3 * D;
    const float sc = 0.125f * 1.44269504f;  // 1/sqrt(64) * log2(e)

    u16* ws    = (u16*)d_ws;
    u16* Xb    = ws;
    u16* WtIn  = Xb + (size_t)M * D;
    u16* WtOut = WtIn + (size_t)N1 * D;
    u16* qkvb  = WtOut + (size_t)D * D;
    u16* attnb = qkvb + (size_t)M * N1;
    u16* Vt    = attnb + (size_t)M * D;    // fresh memory (gemm1 reads Xb)

    prep<<<8192, 256, 0, stream>>>(x, w_in, w_out, Xb, WtIn, WtOut);
    gemm1_256<<<(M / 256) * (N1 / 256), 512, 0, stream>>>(
        Xb, WtIn, b_in, qkvb, Vt, sc);
    attn_kernel<<<512, 256, 0, stream>>>(qkvb, Vt, attnb);
    gemm_bt<64, 128><<<(M / 64) * (D / 128), 256, 0, stream>>>(
        attnb, WtOut, b_out, d_out, M, D, D, 1, 0, 1.f, nullptr, 1 << 30);
}

// Round 6
// 176.134 us; speedup vs baseline: 1.1497x; 1.1497x over previous
//
#include <hip/hip_runtime.h>
#include <hip/hip_bf16.h>

typedef __attribute__((ext_vector_type(8))) short short8;
typedef __attribute__((ext_vector_type(4))) short s16x4;
typedef __attribute__((ext_vector_type(4))) float f32x4;
typedef unsigned short u16;

// round-to-nearest-even fp32 -> bf16
__device__ inline u16 f2bf(float f) {
    union { float f; unsigned u; } x{f};
    unsigned r = (x.u + 0x7fff + ((x.u >> 16) & 1)) >> 16;
    return (u16)r;
}

// pack two fp32 -> packed bf16 pair (round-half-up via +0x8000, then v_perm)
__device__ inline unsigned pkbf(float hi, float lo) {
    unsigned a = __builtin_bit_cast(unsigned, hi) + 0x8000u;
    unsigned b = __builtin_bit_cast(unsigned, lo) + 0x8000u;
    return __builtin_amdgcn_perm(a, b, 0x07060302u);
}

// async 16B global -> LDS (wave-uniform base + lane*16 layout)
__device__ inline void glds16(const u16* g, u16* l) {
    __builtin_amdgcn_global_load_lds(
        (const __attribute__((address_space(1))) void*)g,
        (__attribute__((address_space(3))) void*)l, 16, 0, 0);
}

// ---------------- fused prep: cvt x -> bf16 | transpose w_in | w_out --------
__global__ __launch_bounds__(256) void prep(const float* __restrict__ x,
                                            const float* __restrict__ w_in,
                                            const float* __restrict__ w_out,
                                            u16* __restrict__ Xb,
                                            u16* __restrict__ WtIn,
                                            u16* __restrict__ WtOut) {
    __shared__ float tile[32][33];
    int bx = blockIdx.x, tid = threadIdx.x;
    if (bx < 4096) {
        int i = (bx * 256 + tid) * 4;
        float4 v = *(const float4*)&x[i];
        uint2 o;
        o.x = (unsigned)f2bf(v.x) | ((unsigned)f2bf(v.y) << 16);
        o.y = (unsigned)f2bf(v.z) | ((unsigned)f2bf(v.w) << 16);
        *(uint2*)&Xb[i] = o;
        return;
    }
    const float* W; u16* Wt; int K, N, n0, k0;
    if (bx < 7168) {
        int b2 = bx - 4096;                 // w_in: K=1024, N=3072
        W = w_in; Wt = WtIn; K = 1024; N = 3072;
        n0 = (b2 % 96) * 32; k0 = (b2 / 96) * 32;
    } else {
        int b3 = bx - 7168;                 // w_out: K=1024, N=1024
        W = w_out; Wt = WtOut; K = 1024; N = 1024;
        n0 = (b3 & 31) * 32; k0 = (b3 >> 5) * 32;
    }
    int tx = tid & 31, ty = tid >> 5;
    for (int i = 0; i < 32; i += 8)
        tile[ty + i][tx] = W[(size_t)(k0 + ty + i) * N + n0 + tx];
    __syncthreads();
    for (int i = 0; i < 32; i += 8)
        Wt[(size_t)(n0 + ty + i) * K + k0 + tx] = f2bf(tile[tx][ty + i]);
}

// ---------------- GEMM: C[M][N] = A[M][K] @ Bt[N][K]^T + bias ---------------
// Round 14: REVERT of the 256x256 8-phase gemm1 port (rounds 12-13: 76.6 then
// 66.8us vs this structure's 41.8us — the phase/vmcnt schedule never engaged;
// MfmaUtil 12-14%, both pipes idle, 1 block/CU barrier-bound). This 128x128
// 2-barrier structure measured 616 TF on gemm1 — at its known structural
// ceiling for K=1024 (catalog m248: 2ph = 655-666 TF). gemm1: vt != nullptr
// fuses the V^T scatter from the LDS-staged C tile. gemm2 uses 64x128
// (512 blocks = 2/CU; 128x128 was 1/CU at ~330 TF).
#define BK 64
template<int TBM, int TBN>
__global__ __launch_bounds__(256) void gemm_bt(const u16* __restrict__ A,
                                               const u16* __restrict__ Bt,
                                               const float* __restrict__ bias,
                                               void* __restrict__ C,
                                               int M, int N, int K, int c_is_f32,
                                               int qcols, float qscale,
                                               u16* __restrict__ vt, int vcol0) {
    __shared__ u16 smem[TBM * BK + TBN * BK + 2048];
    u16* As = smem;
    u16* Bs = smem + TBM * BK;

    int tid = threadIdx.x;
    int wave = tid >> 6, lane = tid & 63;
    int quad = lane >> 4, l16 = lane & 15;
    int wm = (wave >> 1) * (TBM / 2), wn = (wave & 1) * (TBN / 2);
    constexpr int MI = TBM / 32, NJ = TBN / 32;

    int nm = M / TBM, nn = N / TBN;
    const int GM = 8;
    int per_group = GM * nn;
    int group = blockIdx.x / per_group;
    int rem = blockIdx.x % per_group;
    int first_m = group * GM;
    int gsz = (nm - first_m < GM) ? (nm - first_m) : GM;
    int m0 = (first_m + rem % gsz) * TBM;
    int n0 = (rem / gsz) * TBN;

    f32x4 acc[MI][NJ] = {};

    for (int k0 = 0; k0 < K; k0 += BK) {
        __syncthreads();
        for (int i = 0; i < TBM * 8 / 256; i++) {
            int c = tid + i * 256;
            int r = c >> 3, cc = c & 7;
            int gsrc = (cc ^ (r & 7)) * 8;          // XOR swizzle
            glds16(&A[(size_t)(m0 + r) * K + k0 + gsrc], As + c * 8);
        }
        for (int i = 0; i < TBN * 8 / 256; i++) {
            int c = tid + i * 256;
            int r = c >> 3, cc = c & 7;
            int gsrc = (cc ^ (r & 7)) * 8;
            glds16(&Bt[(size_t)(n0 + r) * K + k0 + gsrc], Bs + c * 8);
        }
        __syncthreads();
        for (int ks = 0; ks < 2; ks++) {
            short8 af[MI], bf[NJ];
            for (int i = 0; i < MI; i++) {
                int row = wm + i * 16 + l16;
                int slot = (ks * 4 + quad) ^ (row & 7);
                af[i] = *(short8*)&As[row * BK + slot * 8];
            }
            for (int j = 0; j < NJ; j++) {
                int row = wn + j * 16 + l16;
                int slot = (ks * 4 + quad) ^ (row & 7);
                bf[j] = *(short8*)&Bs[row * BK + slot * 8];
            }
            for (int i = 0; i < MI; i++)
                for (int j = 0; j < NJ; j++)
                    acc[i][j] = __builtin_amdgcn_mfma_f32_16x16x32_bf16(
                        af[i], bf[j], acc[i][j], 0, 0, 0);
        }
    }

    if (c_is_f32) {
        for (int i = 0; i < MI; i++)
            for (int j = 0; j < NJ; j++) {
                int col = n0 + wn + j * 16 + l16;
                float bv = bias ? bias[col] : 0.f;
                for (int r = 0; r < 4; r++) {
                    int row = m0 + wm + i * 16 + quad * 4 + r;
                    ((float*)C)[(size_t)row * N + col] = acc[i][j][r] + bv;
                }
            }
    } else {
        __syncthreads();
        u16 (*buf)[136] = (u16(*)[136])smem;
        for (int i = 0; i < MI; i++)
            for (int j = 0; j < NJ; j++) {
                int col = wn + j * 16 + l16;
                float bv = bias ? bias[n0 + col] : 0.f;
                float scl = (n0 + col < qcols) ? qscale : 1.f;
                for (int r = 0; r < 4; r++)
                    buf[wm + i * 16 + quad * 4 + r][col] =
                        f2bf((acc[i][j][r] + bv) * scl);
            }
        __syncthreads();
        u16* Cb = (u16*)C;
        for (int it = 0; it < TBM * 16 / 256; it++) {
            int c = tid + it * 256;
            int row = c / (TBN / 8), k8 = c % (TBN / 8);
            uint4 v = *(uint4*)&buf[row][k8 * 8];
            *(uint4*)&Cb[(size_t)(m0 + row) * N + n0 + k8 * 8] = v;
        }
        // fused V^T scatter: vt[b, h, dh, S] <- buf^T for V-range columns.
        if (vt && n0 >= vcol0) {
            int b = m0 >> 11, s0 = m0 & 2047;
            int hbase = (n0 - vcol0) >> 6;
            for (int pass = 0; pass < TBN / 16; pass++) {
                int col = pass * 16 + (tid >> 4);
                int so = (tid & 15) * 8;
                alignas(16) u16 tmp[8];
                for (int r = 0; r < 8; r++) tmp[r] = buf[so + r][col];
                int h = hbase + (col >> 6), dh = col & 63;
                *(uint4*)&vt[(size_t)((b * 16 + h) * 64 + dh) * 2048 + s0 + so] =
                    __builtin_bit_cast(uint4, tmp);
            }
        }
    }
}

// ---------------- flash attention (causal), 32 q-rows per wave --------------
// (dual chains, chain-sequenced schedule, setprio, O^T epilogue, 2 blocks/CU)
__global__ __launch_bounds__(256, 2) void attn_kernel(const u16* __restrict__ qkv,
                                                      const u16* __restrict__ VT,
                                                      u16* __restrict__ out) {
    const int S = 2048, D = 1024, stride = 3072;
    int idx = blockIdx.x;                 // 512 blocks
    int slot = idx >> 8;                  // 0: heavy half, 1: light half
    int r5 = idx & 255;
    int p = r5 >> 5, bh = r5 & 31;
    int qt = slot ? p : 15 - p;           // q-tile (128 rows) index
    int b = bh >> 4, h = bh & 15;
    int tid = threadIdx.x;                // 256
    int wave = tid >> 6, lane = tid & 63;
    int quad = lane >> 4, l16 = lane & 15;

    __shared__ u16 Klds[2][2][64 * 64];   // [dbuf][chain]; XOR-swizzled rows
    __shared__ u16 Vlds[2][2][64 * 64];

    const u16* Qp = qkv + (size_t)(b * S) * stride + h * 64;
    const u16* Kp = Qp + D;
    const u16* Vtp = VT + (size_t)bh * 64 * S;

    // Q fragments: [q-half][k-half]; wave owns rows qt*128 + wave*32 + 0..31
    short8 qf[2][2];
    for (int qh = 0; qh < 2; qh++) {
        int qrow = qt * 128 + wave * 32 + qh * 16 + l16;
        qf[qh][0] = *(const short8*)&Qp[(size_t)qrow * stride + quad * 8];
        qf[qh][1] = *(const short8*)&Qp[(size_t)qrow * stride + 32 + quad * 8];
    }

    auto stage = [&](int kt, int bsel, int ch) {
        for (int i = 0; i < 2; i++) {
            int c = tid + i * 256;        // 512 chunks of 16B each for K and V
            int rr = c >> 3, cc = c & 7;
            int gsrc = (cc ^ (rr & 7)) * 8;
            glds16(&Kp[(size_t)(kt * 64 + rr) * stride + gsrc],
                   &Klds[bsel][ch][c * 8]);
            glds16(&Vtp[(size_t)rr * S + kt * 64 + gsrc],
                   &Vlds[bsel][ch][c * 8]);
        }
    };

    stage(0, 0, 0);
    stage(1, 0, 1);

    f32x4 O[4][2] = {};                   // [db][qh], O^T fragments
    float ls[2] = {0.f, 0.f};             // row-sum partials per q-half

    int np = qt + 1;                      // pairs of 64-k tiles (exact causal)
    for (int j = 0; j < np; j++) {
        int cur = j & 1;
        __syncthreads();                  // drains DMA for this pair
        if (j + 1 < np) {
            stage(2 * (j + 1), cur ^ 1, 0);
            stage(2 * (j + 1) + 1, cur ^ 1, 1);
        }
        bool last = (j == qt);

        // ---- QK^T for one chain -> st[qh][nb]
        auto qk = [&](int ch, f32x4 st[2][4]) {
            short8 kf[4][2];
            for (int nb = 0; nb < 4; nb++) {
                int rr = nb * 16 + l16;
                int s0 = ((0 + quad) ^ (rr & 7)) * 8;
                int s1 = ((4 + quad) ^ (rr & 7)) * 8;
                kf[nb][0] = *(short8*)&Klds[cur][ch][rr * 64 + s0];
                kf[nb][1] = *(short8*)&Klds[cur][ch][rr * 64 + s1];
            }
            for (int qh = 0; qh < 2; qh++)
                for (int nb = 0; nb < 4; nb++) {
                    f32x4 t = {};
                    t = __builtin_amdgcn_mfma_f32_16x16x32_bf16(
                        kf[nb][0], qf[qh][0], t, 0, 0, 0);
                    t = __builtin_amdgcn_mfma_f32_16x16x32_bf16(
                        kf[nb][1], qf[qh][1], t, 0, 0, 0);
                    st[qh][nb] = t;
                }
        };
        // ---- softmax numerators + pack for one chain
        auto sm = [&](int ch, f32x4 st[2][4], s16x4 pfc[2][4]) {
            for (int qh = 0; qh < 2; qh++) {
                if (last) {
                    int qabs = qt * 128 + wave * 32 + qh * 16 + l16;
                    for (int nb = 0; nb < 4; nb++) {
                        int kb0 = (2 * j + ch) * 64 + nb * 16 + quad * 4;
                        for (int r = 0; r < 4; r++) {
                            float e = __builtin_amdgcn_exp2f(st[qh][nb][r]);
                            st[qh][nb][r] = (kb0 + r <= qabs) ? e : 0.f;
                        }
                    }
                } else {
                    for (int nb = 0; nb < 4; nb++)
                        for (int r = 0; r < 4; r++)
                            st[qh][nb][r] = __builtin_amdgcn_exp2f(st[qh][nb][r]);
                }
                for (int nb = 0; nb < 4; nb++) {
                    ls[qh] += (st[qh][nb][0] + st[qh][nb][1]) +
                              (st[qh][nb][2] + st[qh][nb][3]);
                    uint2 pk;
                    pk.x = pkbf(st[qh][nb][1], st[qh][nb][0]);
                    pk.y = pkbf(st[qh][nb][3], st[qh][nb][2]);
                    pfc[qh][nb] = __builtin_bit_cast(s16x4, pk);
                }
            }
        };
        // ---- PV for one chain (O^T accumulate)
        auto pv = [&](int ch, s16x4 pfc[2][4]) {
            for (int db = 0; db < 4; db++) {
                int rr = db * 16 + l16;
                for (int kc = 0; kc < 4; kc++) {
                    int g = kc * 2 + (quad >> 1);
                    int sl = g ^ (rr & 7);
                    int off = rr * 64 + sl * 8 + (quad & 1) * 4;
                    s16x4 vf = *(s16x4*)&Vlds[cur][ch][off];
                    for (int qh = 0; qh < 2; qh++)
                        O[db][qh] = __builtin_amdgcn_mfma_f32_16x16x16bf16_1k(
                            vf, pfc[qh][kc], O[db][qh], 0, 0, 0);
                }
            }
        };

        f32x4 stA[2][4], stB[2][4];
        s16x4 pfA[2][4], pfB[2][4];

        __builtin_amdgcn_s_setprio(1);
        qk(0, stA);
        __builtin_amdgcn_s_setprio(0);
        sm(0, stA, pfA);
        __builtin_amdgcn_s_setprio(1);
        qk(1, stB);                       // MFMA cluster: chain-B QK ...
        pv(0, pfA);                       // ... + chain-A PV (independent of
        __builtin_amdgcn_s_setprio(0);    //     chain-B softmax -> overlaps it)
        sm(1, stB, pfB);
        __builtin_amdgcn_s_setprio(1);
        pv(1, pfB);
        __builtin_amdgcn_s_setprio(0);
    }

    // epilogue: O^T -> each lane holds dh=db*16+quad*4+r for its own q=l16.
    for (int qh = 0; qh < 2; qh++) {
        float v = ls[qh];
        v += __shfl_xor(v, 16);
        v += __shfl_xor(v, 32);           // full row sum for q=l16
        float rinv = 1.f / v;
        int qrow = qt * 128 + wave * 32 + qh * 16 + l16;
        for (int db = 0; db < 4; db++) {
            uint2 o;
            o.x = pkbf(O[db][qh][1] * rinv, O[db][qh][0] * rinv);
            o.y = pkbf(O[db][qh][3] * rinv, O[db][qh][2] * rinv);
            *(uint2*)&out[(size_t)(b * S + qrow) * D + h * 64 + db * 16 +
                          quad * 4] = o;
        }
    }
}

// ---------------------------------------------------------------------------
extern "C" void kernel_launch(void* const* d_in, const int* in_sizes, int n_in,
                              void* d_out, int out_size, void* d_ws, size_t ws_size,
                              hipStream_t stream) {
    const float* x     = (const float*)d_in[0];
    const float* w_in  = (const float*)d_in[1];
    const float* b_in  = (const float*)d_in[2];
    const float* w_out = (const float*)d_in[3];
    const float* b_out = (const float*)d_in[4];

    const int Bsz = 2, S = 2048, D = 1024, H = 16;
    const int M = Bsz * S;
    const int N1 = 3 * D;
    const float sc = 0.125f * 1.44269504f;  // 1/sqrt(64) * log2(e)

    u16* ws    = (u16*)d_ws;
    u16* Xb    = ws;
    u16* WtIn  = Xb + (size_t)M * D;
    u16* WtOut = WtIn + (size_t)N1 * D;
    u16* qkvb  = WtOut + (size_t)D * D;
    u16* attnb = qkvb + (size_t)M * N1;
    u16* Vt    = attnb + (size_t)M * D;    // fresh memory (gemm1 reads Xb)

    prep<<<8192, 256, 0, stream>>>(x, w_in, w_out, Xb, WtIn, WtOut);
    gemm_bt<128, 128><<<(M / 128) * (N1 / 128), 256, 0, stream>>>(
        Xb, WtIn, b_in, qkvb, M, N1, D, 0, D, sc, Vt, 2048);
    attn_kernel<<<512, 256, 0, stream>>>(qkvb, Vt, attnb);
    gemm_bt<64, 128><<<(M / 64) * (D / 128), 256, 0, stream>>>(
        attnb, WtOut, b_out, d_out, M, D, D, 1, 0, 1.f, nullptr, 1 << 30);
}